// Round 9
// baseline (282.518 us; speedup 1.0000x reference)
//
#include <hip/hip_runtime.h>
#include <cstdint>
#include <cstddef>

#define NEG_SLOPE 0.2f

typedef __bf16 bf16x8 __attribute__((ext_vector_type(8)));
typedef float  f32x4  __attribute__((ext_vector_type(4)));

__device__ inline unsigned int bf16pair(float a, float b) {
    unsigned int ua = __float_as_uint(a), ub = __float_as_uint(b);
    ua += 0x7fffu + ((ua >> 16) & 1u);
    ub += 0x7fffu + ((ub >> 16) & 1u);
    return (ua >> 16) | (ub & 0xffff0000u);
}
__device__ inline unsigned short bf16r(float x) {
    unsigned int u = __float_as_uint(x);
    u += 0x7fffu + ((u >> 16) & 1u);
    return (unsigned short)(u >> 16);
}

// ---------------------------------------------------------------------------
// Prep: blocks 0..7 = W transpose+cast (Wt[n][k] = bf16(W[k][n]));
// blocks 8.. = CSR rank pass (rank[e] = atomicAdd(deg[dst[e]])), x4/thread.
// Both are LDS-light (16.6 KB) so rank keeps 8 blocks/CU occupancy --
// the R8 lesson: fusing rank into the 52KB-LDS GEMM throttled it to 3/CU.
// ---------------------------------------------------------------------------
__global__ __launch_bounds__(256) void prep_kernel(
    const float* __restrict__ W1, const float* __restrict__ W2,
    unsigned short* __restrict__ Wt1, unsigned short* __restrict__ Wt2,
    const int* __restrict__ dst, int* __restrict__ deg,
    int* __restrict__ rank, int E)
{
    __shared__ float tile[64][65];
    if (blockIdx.x < 8) {
        const float* W = (blockIdx.x < 4) ? W1 : W2;
        unsigned short* Wt = (blockIdx.x < 4) ? Wt1 : Wt2;
        const int tb = blockIdx.x & 3;
        const int k0 = (tb >> 1) * 64, n0 = (tb & 1) * 64;
        const int c = threadIdx.x & 63, r4 = threadIdx.x >> 6;
#pragma unroll
        for (int i = 0; i < 16; ++i) {
            const int r = i * 4 + r4;
            tile[r][c] = W[(size_t)(k0 + r) * 128 + n0 + c];
        }
        __syncthreads();
#pragma unroll
        for (int i = 0; i < 16; ++i) {
            const int nn = i * 4 + r4;
            Wt[(size_t)(n0 + nn) * 128 + k0 + c] = bf16r(tile[c][nn]);
        }
        return;
    }
    const int bid = blockIdx.x - 8;
    const int e4 = (bid * 256 + threadIdx.x) * 4;
    if (e4 + 4 <= E) {
        const int4 d = *(const int4*)&dst[e4];
        int4 r;
        r.x = atomicAdd(&deg[d.x], 1);
        r.y = atomicAdd(&deg[d.y], 1);
        r.z = atomicAdd(&deg[d.z], 1);
        r.w = atomicAdd(&deg[d.w], 1);
        *(int4*)&rank[e4] = r;
    } else {
        for (int e = e4; e < E; ++e) rank[e] = atomicAdd(&deg[dst[e]], 1);
    }
}

// ---------------------------------------------------------------------------
// MFMA GEMM: feat16 = bf16(X @ W), fused el/er. Block = 64 rows x 128 cols.
// Wave w owns cols w*32..+31 (= exactly head w) for ALL 64 rows; B-frags for
// its 2 col-tiles x 4 K-steps live in 32 VGPRs, loaded once from global Wt
// (L2-resident, identical across blocks) -- the 34KB sW LDS stage is gone.
// LDS: sX 17KB + sF 17KB (epilogue repack, XOR-swizzled by (row>>2)&3 so the
// u16 writes are conflict-free; R8 measured 550k conflicts unswizzled).
// 34.8KB total -> 4 blocks/CU; 782-block grid = one occupancy round.
// Frag layouts (m89/m120-verified): A[m=lane&15][k=(lane>>4)*8+j];
// C/D col=lane&15, row=(lane>>4)*4+reg.
// ---------------------------------------------------------------------------
template <bool XBF16>
__global__ __launch_bounds__(256, 4) void gemm_attn_kernel(
    const void* __restrict__ Xv, const unsigned short* __restrict__ Wt,
    const float* __restrict__ al, const float* __restrict__ ar,
    unsigned short* __restrict__ feat16, float* __restrict__ el,
    float* __restrict__ er, int n)
{
    __shared__ unsigned short sX[64][136];   // 17.4 KB
    __shared__ unsigned short sF[64][136];   // 17.4 KB

    const int t = threadIdx.x;
    const int rowbase = blockIdx.x * 64;

    if (XBF16) {
        const unsigned short* X = (const unsigned short*)Xv;
#pragma unroll
        for (int i = 0; i < 4; ++i) {
            const int idx = t + 256 * i;     // 0..1023 uint4s
            const int row = idx >> 4;
            const int q   = idx & 15;
            int g = rowbase + row; if (g >= n) g = n - 1;
            *(uint4*)&sX[row][q * 8] = *(const uint4*)&X[(size_t)g * 128 + q * 8];
        }
    } else {
        const float* X = (const float*)Xv;
#pragma unroll
        for (int i = 0; i < 8; ++i) {
            const int idx = t + 256 * i;     // 0..2047 float4s
            const int row = idx >> 5;
            const int kq  = (idx & 31) * 4;
            int g = rowbase + row; if (g >= n) g = n - 1;
            const float4 v = *(const float4*)&X[(size_t)g * 128 + kq];
            uint2 pk;
            pk.x = bf16pair(v.x, v.y);
            pk.y = bf16pair(v.z, v.w);
            *(uint2*)&sX[row][kq] = pk;
        }
    }

    const int lane = t & 63;
    const int w    = t >> 6;                 // wave = head = cols w*32..+31
    const int m    = lane & 15;
    const int g4   = lane >> 4;

    // B fragments from global Wt (no LDS round-trip)
    bf16x8 bfr[2][4];
#pragma unroll
    for (int tile = 0; tile < 2; ++tile)
#pragma unroll
        for (int ks = 0; ks < 4; ++ks)
            bfr[tile][ks] = *(const bf16x8*)
                &Wt[(size_t)(w * 32 + tile * 16 + m) * 128 + ks * 32 + g4 * 8];

    __syncthreads();

    const int n0 = w * 32 + m, n1 = n0 + 16;
    const float al0 = al[n0], ar0 = ar[n0];
    const float al1 = al[n1], ar1 = ar[n1];
    const int swz = g4 << 3;                 // writer swizzle: (row>>2)&3 == g4

#pragma unroll
    for (int rt = 0; rt < 4; ++rt) {
        bf16x8 a[4];
#pragma unroll
        for (int ks = 0; ks < 4; ++ks)
            a[ks] = *(const bf16x8*)&sX[rt * 16 + m][ks * 32 + g4 * 8];
        f32x4 acc0 = {0.f, 0.f, 0.f, 0.f}, acc1 = {0.f, 0.f, 0.f, 0.f};
#pragma unroll
        for (int ks = 0; ks < 4; ++ks) {
            acc0 = __builtin_amdgcn_mfma_f32_16x16x32_bf16(a[ks], bfr[0][ks], acc0, 0, 0, 0);
            acc1 = __builtin_amdgcn_mfma_f32_16x16x32_bf16(a[ks], bfr[1][ks], acc1, 0, 0, 0);
        }
#pragma unroll
        for (int r = 0; r < 4; ++r) {
            const int row = rt * 16 + g4 * 4 + r;
            sF[row][(n0) ^ swz]      = bf16r(acc0[r]);
            sF[row][(n1) ^ swz]      = bf16r(acc1[r]);
            float pl = acc0[r] * al0 + acc1[r] * al1;
            float pr = acc0[r] * ar0 + acc1[r] * ar1;
            pl += __shfl_xor(pl, 1); pr += __shfl_xor(pr, 1);
            pl += __shfl_xor(pl, 2); pr += __shfl_xor(pr, 2);
            pl += __shfl_xor(pl, 4); pr += __shfl_xor(pr, 4);
            pl += __shfl_xor(pl, 8); pr += __shfl_xor(pr, 8);
            if (m == 0 && rowbase + row < n) {
                el[(size_t)(rowbase + row) * 4 + w] = pl;
                er[(size_t)(rowbase + row) * 4 + w] = pr;
            }
        }
    }

    __syncthreads();
    {
        const int row = t >> 2;              // 0..63
        const int q   = t & 3;
        const int g   = rowbase + row;
        const int sw_ = ((row >> 2) & 3) << 3;
        if (g < n) {
#pragma unroll
            for (int i = 0; i < 4; ++i) {
                const int c0 = q * 8 + i * 32;
                *(uint4*)&feat16[(size_t)g * 128 + c0] =
                    *(const uint4*)&sF[row][c0 ^ sw_];
            }
        }
    }
}

// ---------------------------------------------------------------------------
// NOTE: assumes n % 4 == 0 (n = 50000 here).
__global__ __launch_bounds__(1024) void scan_kernel(
    const int* __restrict__ deg, int* __restrict__ off, int n)
{
    __shared__ int wsums[16];
    __shared__ int s_carry;
    const int tid  = threadIdx.x;
    const int lane = tid & 63;
    const int wid  = tid >> 6;

    if (tid == 0) { s_carry = 0; off[0] = 0; }
    __syncthreads();

    const int n4 = n >> 2;
    const int4* __restrict__ deg4 = (const int4*)deg;

    for (int base = 0; base < n4; base += 1024) {
        const int i4 = base + tid;
        int4 v = make_int4(0, 0, 0, 0);
        if (i4 < n4) v = deg4[i4];
        const int t0 = v.x, t1 = t0 + v.y, t2 = t1 + v.z, t3 = t2 + v.w;

        int x = t3;
#pragma unroll
        for (int d = 1; d < 64; d <<= 1) {
            int y = __shfl_up(x, d);
            if (lane >= d) x += y;
        }
        if (lane == 63) wsums[wid] = x;
        __syncthreads();

        if (wid == 0 && lane < 16) {
            int xx = wsums[lane];
#pragma unroll
            for (int d = 1; d < 16; d <<= 1) {
                int y = __shfl_up(xx, d);
                if (lane >= d) xx += y;
            }
            wsums[lane] = xx;
        }
        __syncthreads();

        const int wp   = (wid == 0) ? 0 : wsums[wid - 1];
        const int excl = s_carry + wp + (x - t3);
        if (i4 < n4) {
            off[4 * i4 + 1] = excl + t0;
            off[4 * i4 + 2] = excl + t1;
            off[4 * i4 + 3] = excl + t2;
            off[4 * i4 + 4] = excl + t3;
        }
        __syncthreads();
        if (tid == 0) s_carry += wsums[15];
        __syncthreads();
    }
}

__global__ void place_kernel(const int* __restrict__ src, const int* __restrict__ dst,
                             const int* __restrict__ off, const int* __restrict__ rank,
                             int* __restrict__ csr_src, int E)
{
    const int e4 = (blockIdx.x * blockDim.x + threadIdx.x) * 4;
    if (e4 + 4 <= E) {
        const int4 s = *(const int4*)&src[e4];
        const int4 d = *(const int4*)&dst[e4];
        const int4 r = *(const int4*)&rank[e4];
        const int o0 = off[d.x], o1 = off[d.y], o2 = off[d.z], o3 = off[d.w];
        csr_src[o0 + r.x] = s.x;
        csr_src[o1 + r.y] = s.y;
        csr_src[o2 + r.z] = s.z;
        csr_src[o3 + r.w] = s.w;
    } else {
        for (int e = e4; e < E; ++e)
            csr_src[off[dst[e]] + rank[e]] = src[e];
    }
}

// ---------------------------------------------------------------------------
// Aggregation: one wave per destination node, 16-deep load batching.
// LAYER1: resid = fp32 x, out = bf16 h1. LAYER2: resid = bf16 h1, out = fp32
// head-mean. leaky_relu(x) = max(x, 0.2x). Lane owns dim pair (2l, 2l+1) of
// head l>>4 -> per-edge feat16 read is one coalesced 256B wave-load.
// ---------------------------------------------------------------------------
template <bool LAYER2>
__global__ __launch_bounds__(256) void agg_kernel(
    const int* __restrict__ off, const int* __restrict__ csr_src,
    const unsigned short* __restrict__ feat16, const float* __restrict__ el,
    const float* __restrict__ er, const void* __restrict__ resid,
    const float* __restrict__ bias, void* __restrict__ out, int n)
{
    const int lane = threadIdx.x & 63;
    const int node = blockIdx.x * 4 + (threadIdx.x >> 6);
    if (node >= n) return;

    const int h  = lane >> 4;
    const int d0 = 2 * lane;

    const float erh = er[(size_t)node * 4 + h];
    const unsigned int* __restrict__ fb = (const unsigned int*)feat16;

    const int beg = off[node], end = off[node + 1];

    float acc0 = 0.f, acc1 = 0.f, sw = 0.f;
    int j = beg;

    for (; j + 16 <= end; j += 16) {
        int s[16]; float ev[16]; unsigned int uv[16];
#pragma unroll
        for (int q = 0; q < 16; ++q) s[q] = csr_src[j + q];
#pragma unroll
        for (int q = 0; q < 16; ++q) ev[q] = el[(size_t)s[q] * 4 + h];
#pragma unroll
        for (int q = 0; q < 16; ++q) uv[q] = fb[(size_t)s[q] * 64 + lane];
#pragma unroll
        for (int q = 0; q < 16; ++q) {
            float a = ev[q] + erh;
            a = fmaxf(a, NEG_SLOPE * a);
            const float wq = __expf(a);
            acc0 += wq * __uint_as_float(uv[q] << 16);
            acc1 += wq * __uint_as_float(uv[q] & 0xffff0000u);
            sw += wq;
        }
    }
    for (; j + 4 <= end; j += 4) {
        int s[4]; float ev[4]; unsigned int uv[4];
#pragma unroll
        for (int q = 0; q < 4; ++q) s[q] = csr_src[j + q];
#pragma unroll
        for (int q = 0; q < 4; ++q) ev[q] = el[(size_t)s[q] * 4 + h];
#pragma unroll
        for (int q = 0; q < 4; ++q) uv[q] = fb[(size_t)s[q] * 64 + lane];
#pragma unroll
        for (int q = 0; q < 4; ++q) {
            float a = ev[q] + erh;
            a = fmaxf(a, NEG_SLOPE * a);
            const float wq = __expf(a);
            acc0 += wq * __uint_as_float(uv[q] << 16);
            acc1 += wq * __uint_as_float(uv[q] & 0xffff0000u);
            sw += wq;
        }
    }
    for (; j < end; ++j) {
        const int s = csr_src[j];
        float a = el[(size_t)s * 4 + h] + erh;
        a = fmaxf(a, NEG_SLOPE * a);
        const float wq = __expf(a);
        const unsigned int u = fb[(size_t)s * 64 + lane];
        acc0 += wq * __uint_as_float(u << 16);
        acc1 += wq * __uint_as_float(u & 0xffff0000u);
        sw += wq;
    }

    const float inv = 1.f / fmaxf(sw, 1e-9f);
    float rx, ry;
    if (!LAYER2) {
        const float2 rs = *(const float2*)((const float*)resid + (size_t)node * 128 + d0);
        rx = rs.x; ry = rs.y;
    } else {
        const unsigned int u =
            *(const unsigned int*)((const unsigned short*)resid + (size_t)node * 128 + d0);
        rx = __uint_as_float(u << 16);
        ry = __uint_as_float(u & 0xffff0000u);
    }
    float v0 = acc0 * inv + rx + bias[d0];
    float v1 = acc1 * inv + ry + bias[d0 + 1];

    if (!LAYER2) {
        v0 = (v0 > 0.f) ? v0 : expm1f(v0);
        v1 = (v1 > 0.f) ? v1 : expm1f(v1);
        *(unsigned int*)((unsigned short*)out + (size_t)node * 128 + d0) = bf16pair(v0, v1);
    } else {
        float s0 = v0, s1 = v1;
        s0 += __shfl_xor(s0, 16); s1 += __shfl_xor(s1, 16);
        s0 += __shfl_xor(s0, 32); s1 += __shfl_xor(s1, 32);
        if (lane < 16)
            *(float2*)((float*)out + (size_t)node * 32 + 2 * lane) =
                make_float2(s0 * 0.25f, s1 * 0.25f);
    }
}

// ---------------------------------------------------------------------------
extern "C" void kernel_launch(void* const* d_in, const int* in_sizes, int n_in,
                              void* d_out, int out_size, void* d_ws, size_t ws_size,
                              hipStream_t stream)
{
    const float* x   = (const float*)d_in[0];
    const float* W1  = (const float*)d_in[1];
    const float* al1 = (const float*)d_in[2];
    const float* ar1 = (const float*)d_in[3];
    const float* b1  = (const float*)d_in[4];
    const float* W2  = (const float*)d_in[5];
    const float* al2 = (const float*)d_in[6];
    const float* ar2 = (const float*)d_in[7];
    const float* b2  = (const float*)d_in[8];
    const int*   src = (const int*)d_in[9];
    const int*   dst = (const int*)d_in[10];

    const int n = in_sizes[0] / 128;
    const int E = in_sizes[9];
    float* out = (float*)d_out;

    char* p = (char*)d_ws;
    unsigned short* h1b    = (unsigned short*)p; p += (size_t)n * 128 * sizeof(unsigned short);
    unsigned short* feat16 = (unsigned short*)p; p += (size_t)n * 128 * sizeof(unsigned short);
    float* el    = (float*)p;          p += (size_t)n * 4 * sizeof(float);
    float* er    = (float*)p;          p += (size_t)n * 4 * sizeof(float);
    int* off     = (int*)p;            p += (size_t)(n + 1) * sizeof(int);
    int* deg     = (int*)p;            p += (size_t)n * sizeof(int);
    int* rank    = (int*)p;            p += (size_t)E * sizeof(int);
    int* csr     = (int*)p;            p += (size_t)E * sizeof(int);
    unsigned short* wt1 = (unsigned short*)p; p += (size_t)128 * 128 * sizeof(unsigned short);
    unsigned short* wt2 = (unsigned short*)p; p += (size_t)128 * 128 * sizeof(unsigned short);

    hipMemsetAsync(deg, 0, (size_t)n * sizeof(int), stream);

    const int gemm_grid  = (n + 63) / 64;
    const int edge4_grid = (E / 4 + 255) / 256;
    const int agg_grid   = (n + 3) / 4;

    prep_kernel<<<8 + edge4_grid, 256, 0, stream>>>(W1, W2, wt1, wt2, dst, deg, rank, E);
    gemm_attn_kernel<false><<<gemm_grid, 256, 0, stream>>>(x, wt1, al1, ar1, feat16, el, er, n);
    scan_kernel<<<1, 1024, 0, stream>>>(deg, off, n);
    place_kernel<<<edge4_grid, 256, 0, stream>>>(src, dst, off, rank, csr, E);
    agg_kernel<false><<<agg_grid, 256, 0, stream>>>(off, csr, feat16, el, er, x, b1, h1b, n);
    gemm_attn_kernel<true><<<gemm_grid, 256, 0, stream>>>(h1b, wt2, al2, ar2, feat16, el, er, n);
    agg_kernel<true><<<agg_grid, 256, 0, stream>>>(off, csr, feat16, el, er, h1b, b2, out, n);
}